// Round 8
// baseline (649.905 us; speedup 1.0000x reference)
//
#include <hip/hip_runtime.h>
#include <hip/hip_bf16.h>

// LSTMEncoder: B=65536, T=25, I=4, H=64, 2 layers, out = h2 at t=4,9,14,19,24.
// Split-precision matmul (v = hi + lo bf16 pairs) for f32-accurate trajectory:
//   h@W ~= h_hi@W_hi + h_hi@W_lo + h_lo@W_hi  (exact products, f32 MFMA acc)
// Elementwise pure f32 (hw exp2/rcp).
//
// R7:  wave specialization (waves 0-3 = layer 1, 4-7 = layer 2), 1 barrier/iter.
// R8:  pre-split weights into d_ws. R9/R10: LDS squeeze; occupancy capped at
//   2 waves/SIMD by register-resident weights. R11: anti-phase sched: null.
// R12: ew VALU cut (VALUBusy 56->46): null on time. R13: term-major MFMA
//   interleave: -53us (522), absmax bit-identical.
// R14: MB 64->128 (8 mt-tiles/wave, 2x ILP, barriers halved). FAILED on a
//   staging bug: per-timestep x(tt+1) staging runs in the L1 branch (tids
//   0..255) but used m = tid>>2 (rows 0..63 only) -> rows 64..127 read
//   zeros/stale x(0). R15 (this round): SAME design, staging fixed: each L1
//   thread stages TWO rows (m = (tid>>2) + s*64, s=0,1). Numerics otherwise
//   identical to R13 (absmax tripwire: 4.882812e-4).
//
// MFMA 16x16x32 bf16 layouts (measured, learn_hip m89/m120):
//   A[m][k]: m=lane&15, k=(lane>>4)*8+e ; B[k][n]: n=lane&15, k=(lane>>4)*8+e
//   C/D    : col=lane&15, row=(lane>>4)*4+reg

typedef short short8 __attribute__((ext_vector_type(8)));
typedef float floatx4 __attribute__((ext_vector_type(4)));

namespace {
constexpr int T_ = 25;
constexpr int I_ = 4;
constexpr int MB = 128;    // batch rows per block (8 mt-tiles of 16)
constexpr int NMT = MB / 16;
constexpr int HSTR = 72;   // LDS row stride (shorts): 144B, 16B-aligned, 2-way banks
constexpr int XSTR = 24;   // x tile stride (shorts): 48B, 2-way banks
constexpr int XPAD = 8;    // last-row overread pad (q=3 reads offs 24..31)

// Workspace layout, in short8 (16B fragment-row) units.
constexpr int OFF_BX   = 0;
constexpr int OFF_HH0H = 1024;
constexpr int OFF_HH0L = 3072;
constexpr int OFF_IH1H = 5120;
constexpr int OFF_IH1L = 7168;
constexpr int OFF_HH1H = 9216;
constexpr int OFF_HH1L = 11264;

constexpr float SC_SIG  = -1.44269504088896340736f;  // -log2(e)
constexpr float SC_TANH = -2.88539008177792681472f;  // -2*log2(e)
}

// Activation helpers. Inputs of sigm2_/tanhg_ are PRE-SCALED via the weights.
__device__ __forceinline__ float sigm2_(float z) {   // z = -log2e * x
  float t = __builtin_amdgcn_exp2f(z);
  return __builtin_amdgcn_rcpf(1.0f + t);
}
__device__ __forceinline__ float tanhg_(float z) {   // z = -2*log2e * x
  float t = __builtin_amdgcn_exp2f(z);
  return 2.0f * __builtin_amdgcn_rcpf(1.0f + t) - 1.0f;
}
__device__ __forceinline__ float tanhc_(float x) {   // plain tanh (c is unscaled)
  float t = __builtin_amdgcn_exp2f(x * SC_TANH);
  return 2.0f * __builtin_amdgcn_rcpf(1.0f + t) - 1.0f;
}

__device__ __forceinline__ unsigned short f2bf_(float f) {  // RNE f32->bf16 (prep only)
  unsigned u = __float_as_uint(f);
  u += 0x7FFFu + ((u >> 16) & 1u);
  return (unsigned short)(u >> 16);
}
__device__ __forceinline__ float bf2f_(unsigned short s) {
  return __uint_as_float(((unsigned)s) << 16);
}
__device__ __forceinline__ void splitf_(float f, unsigned short& hi, unsigned short& lo) {
  hi = f2bf_(f);
  lo = f2bf_(f - bf2f_(hi));
}

// ---------------------------------------------------------------------------
// Prep kernel: scale by activation constants, then split into fragment-ordered
// hi/lo short8 rows. Runs once; RNE split kept here (free).
// ---------------------------------------------------------------------------
__global__ void prep_weights(const float* __restrict__ Wih0,   // [256,4]
                             const float* __restrict__ Whh0,   // [256,64]
                             const float* __restrict__ Wih1,   // [256,64]
                             const float* __restrict__ Whh1,   // [256,64]
                             unsigned short* __restrict__ ws) {
  const int t = blockIdx.x * 256 + threadIdx.x;
  if (t < 1024) {
    const int lane = t & 63, w = (t >> 6) & 3, g = t >> 8;
    const int l = lane & 15, q = lane >> 4;
    const int n = g * 64 + w * 16 + l;
    const float sc = (g == 2) ? SC_TANH : SC_SIG;
    unsigned short row[8];
#pragma unroll
    for (int e = 0; e < 8; ++e) row[e] = 0;
    if (q < 2) {
#pragma unroll
      for (int e = 0; e < 4; ++e) {
        unsigned short h, lo;
        splitf_(Wih0[n * 4 + e] * sc, h, lo);
        row[e] = h;
        if (q == 0) row[4 + e] = lo;
      }
    }
#pragma unroll
    for (int e = 0; e < 8; ++e) ws[(OFF_BX + t) * 8 + e] = row[e];
  } else if (t < 7168) {
    const int a = (t - 1024) >> 11;    // 0:Whh0 1:Wih1 2:Whh1
    const int r = (t - 1024) & 2047;   // r = g*512 + hf*256 + w*64 + lane
    const int lane = r & 63, w = (r >> 6) & 3, hf = (r >> 8) & 1, g = r >> 9;
    const int l = lane & 15, q = lane >> 4;
    const int n = g * 64 + w * 16 + l;
    const float sc = (g == 2) ? SC_TANH : SC_SIG;
    const float* src = (a == 0) ? Whh0 : (a == 1) ? Wih1 : Whh1;
    const int offH = (a == 0) ? OFF_HH0H : (a == 1) ? OFF_IH1H : OFF_HH1H;
    const int offL = offH + 2048;
#pragma unroll
    for (int e = 0; e < 8; ++e) {
      unsigned short h, lo;
      splitf_(src[n * 64 + hf * 32 + q * 8 + e] * sc, h, lo);
      ws[(offH + r) * 8 + e] = h;
      ws[(offL + r) * 8 + e] = lo;
    }
  }
}

// Term-major round: one MFMA from each of the 4 independent gate chains.
// Data deps (a0..a3 accumulate) + the MFMA sched group force round-robin.
#define R4(A_, b0_, b1_, b2_, b3_)                                           \
  a0 = __builtin_amdgcn_mfma_f32_16x16x32_bf16((A_), (b0_), a0, 0, 0, 0);    \
  a1 = __builtin_amdgcn_mfma_f32_16x16x32_bf16((A_), (b1_), a1, 0, 0, 0);    \
  a2 = __builtin_amdgcn_mfma_f32_16x16x32_bf16((A_), (b2_), a2, 0, 0, 0);    \
  a3 = __builtin_amdgcn_mfma_f32_16x16x32_bf16((A_), (b3_), a3, 0, 0, 0);    \
  __builtin_amdgcn_sched_group_barrier(0x008, 4, 0);

// ---------------------------------------------------------------------------
// Main kernel
// ---------------------------------------------------------------------------
__global__ __launch_bounds__(512, 1)
void lstm2_kernel(const float* __restrict__ x,     // [B,25,4]
                  const float* __restrict__ b0,    // [256]
                  const float* __restrict__ b1,    // [256]
                  const short8* __restrict__ wf,   // pre-split scaled weight frags
                  float* __restrict__ out) {       // [B,5,64]
  // h1(t) lives in H1*[t&1]; h2(t) in H2*[t&1]; x(t) in XB[t&1].
  __shared__ __align__(16) unsigned short H1h[2][MB * HSTR];
  __shared__ __align__(16) unsigned short H1l[2][MB * HSTR];
  __shared__ __align__(16) unsigned short H2h[2][MB * HSTR];
  __shared__ __align__(16) unsigned short H2l[2][MB * HSTR];
  __shared__ __align__(16) unsigned short XB[2][MB * XSTR + XPAD];

  const int tid = threadIdx.x;
  const int lane = tid & 63;
  const int w = tid >> 6;   // 0..7
  const int l = lane & 15;
  const int q = lane >> 4;
  const int mbase = blockIdx.x * MB;

  // ---- init LDS: zero the [1] state buffers (h(-1)=0) + both XB buffers ----
  for (int idx = tid; idx < MB * 64; idx += 512) {
    int m = idx >> 6, k = idx & 63;
    H1h[1][m * HSTR + k] = 0;
    H1l[1][m * HSTR + k] = 0;
    H2h[1][m * HSTR + k] = 0;
    H2l[1][m * HSTR + k] = 0;
  }
  for (int idx = tid; idx < 2 * (MB * XSTR + XPAD); idx += 512) (&XB[0][0])[idx] = 0;
  {  // stage x(0) into XB[0] (truncation split): all 512 threads, 128 rows
    int m = tid >> 2, ii = tid & 3;
    float xv = x[(mbase + m) * (T_ * I_) + ii];
    unsigned u = __float_as_uint(xv);
    float hif = __uint_as_float(u & 0xffff0000u);
    unsigned ul = __float_as_uint(xv - hif);
    XB[0][m * XSTR + ii] = (unsigned short)(u >> 16);
    XB[0][m * XSTR + 4 + ii] = (unsigned short)(u >> 16);
    XB[0][m * XSTR + 8 + ii] = (unsigned short)(ul >> 16);
  }
  __syncthreads();

  if (w < 4) {
    // ==================== LAYER-1 WAVES (0..3) ====================
    const int j = w * 16 + l;  // hidden col owned (all 4 gates)
    short8 B1h[4][2], B1l[4][2], BXf[4];
    floatx4 bias0v[4];
#pragma unroll
    for (int g = 0; g < 4; ++g) {
      BXf[g] = wf[OFF_BX + g * 256 + w * 64 + lane];
#pragma unroll
      for (int hf = 0; hf < 2; ++hf) {
        B1h[g][hf] = wf[OFF_HH0H + (g * 2 + hf) * 256 + w * 64 + lane];
        B1l[g][hf] = wf[OFF_HH0L + (g * 2 + hf) * 256 + w * 64 + lane];
      }
      float bb = b0[g * 64 + j] * ((g == 2) ? SC_TANH : SC_SIG);
      bias0v[g] = (floatx4){bb, bb, bb, bb};
    }
    float c1[4 * NMT];
#pragma unroll
    for (int k = 0; k < 4 * NMT; ++k) c1[k] = 0.f;

#pragma unroll 1
    for (int tt = 0; tt < T_ + 1; ++tt) {
      if (tt < T_) {
        const int p = tt & 1;  // write h1(tt) -> H1*[p]; read h1(tt-1) <- H1*[p^1]
#pragma unroll
        for (int mt = 0; mt < NMT; ++mt) {
          const int row = mt * 16 + l;
          short8 a0h = *(const short8*)&H1h[p ^ 1][row * HSTR + q * 8];
          short8 a1h = *(const short8*)&H1h[p ^ 1][row * HSTR + 32 + q * 8];
          short8 a0l = *(const short8*)&H1l[p ^ 1][row * HSTR + q * 8];
          short8 a1l = *(const short8*)&H1l[p ^ 1][row * HSTR + 32 + q * 8];
          short8 ax  = *(const short8*)&XB[p][row * XSTR + q * 8];
          floatx4 a0 = bias0v[0], a1 = bias0v[1], a2 = bias0v[2], a3 = bias0v[3];
          // 7 term-major rounds; per-gate order identical to the old chain.
          R4(ax,  BXf[0],     BXf[1],     BXf[2],     BXf[3])
          R4(a0h, B1h[0][0],  B1h[1][0],  B1h[2][0],  B1h[3][0])
          R4(a1h, B1h[0][1],  B1h[1][1],  B1h[2][1],  B1h[3][1])
          R4(a0h, B1l[0][0],  B1l[1][0],  B1l[2][0],  B1l[3][0])
          R4(a1h, B1l[0][1],  B1l[1][1],  B1l[2][1],  B1l[3][1])
          R4(a0l, B1h[0][0],  B1h[1][0],  B1h[2][0],  B1h[3][0])
          R4(a1l, B1h[0][1],  B1h[1][1],  B1h[2][1],  B1h[3][1])
#pragma unroll
          for (int r = 0; r < 4; ++r) {
            float si = sigm2_(a0[r]);
            float sf = sigm2_(a1[r]);
            float tg = tanhg_(a2[r]);
            float so = sigm2_(a3[r]);
            float cc = sf * c1[mt * 4 + r] + si * tg;
            c1[mt * 4 + r] = cc;
            float h = so * tanhc_(cc);
            unsigned u = __float_as_uint(h);
            float hif = __uint_as_float(u & 0xffff0000u);
            unsigned ul = __float_as_uint(h - hif);
            const int m = mt * 16 + q * 4 + r;
            H1h[p][m * HSTR + j] = (unsigned short)(u >> 16);
            H1l[p][m * HSTR + j] = (unsigned short)(ul >> 16);
          }
        }
        if (tt + 1 < T_) {
          // stage x(tt+1): 256 L1 threads cover 128 rows -> TWO rows each
          // (R14 bug: m=tid>>2 covered only rows 0..63; rows 64..127 went stale)
#pragma unroll
          for (int s = 0; s < 2; ++s) {
            int m = (tid >> 2) + s * 64, ii = tid & 3;
            float xv = x[(mbase + m) * (T_ * I_) + (tt + 1) * I_ + ii];
            unsigned u = __float_as_uint(xv);
            float hif = __uint_as_float(u & 0xffff0000u);
            unsigned ul = __float_as_uint(xv - hif);
            XB[(tt + 1) & 1][m * XSTR + ii] = (unsigned short)(u >> 16);
            XB[(tt + 1) & 1][m * XSTR + 4 + ii] = (unsigned short)(u >> 16);
            XB[(tt + 1) & 1][m * XSTR + 8 + ii] = (unsigned short)(ul >> 16);
          }
        }
      }
      __syncthreads();  // barrier 1-per-iter, matched with L2 branch
    }
  } else {
    // ==================== LAYER-2 WAVES (4..7) ====================
    const int w2 = w - 4;
    const int j = w2 * 16 + l;
    short8 B2h[4][4], B2l[4][4];  // [0..1]=Wih1, [2..3]=Whh1
    floatx4 bias1v[4];
#pragma unroll
    for (int g = 0; g < 4; ++g) {
#pragma unroll
      for (int hf = 0; hf < 2; ++hf) {
        B2h[g][hf]     = wf[OFF_IH1H + (g * 2 + hf) * 256 + w2 * 64 + lane];
        B2l[g][hf]     = wf[OFF_IH1L + (g * 2 + hf) * 256 + w2 * 64 + lane];
        B2h[g][2 + hf] = wf[OFF_HH1H + (g * 2 + hf) * 256 + w2 * 64 + lane];
        B2l[g][2 + hf] = wf[OFF_HH1L + (g * 2 + hf) * 256 + w2 * 64 + lane];
      }
      float bb = b1[g * 64 + j] * ((g == 2) ? SC_TANH : SC_SIG);
      bias1v[g] = (floatx4){bb, bb, bb, bb};
    }
    float c2[4 * NMT];
#pragma unroll
    for (int k = 0; k < 4 * NMT; ++k) c2[k] = 0.f;

#pragma unroll 1
    for (int tt = 0; tt < T_ + 1; ++tt) {
      if (tt >= 1) {
        const int t2 = tt - 1;   // computing h2(t2)
        const int p2 = t2 & 1;   // read h1(t2) <- H1*[p2], h2(t2-1) <- H2*[p2^1]
        const bool do_out = (t2 % 5 == 4);
        const int kk = t2 / 5;
#pragma unroll
        for (int mt = 0; mt < NMT; ++mt) {
          const int row = mt * 16 + l;
          short8 n0h = *(const short8*)&H1h[p2][row * HSTR + q * 8];
          short8 n1h = *(const short8*)&H1h[p2][row * HSTR + 32 + q * 8];
          short8 n0l = *(const short8*)&H1l[p2][row * HSTR + q * 8];
          short8 n1l = *(const short8*)&H1l[p2][row * HSTR + 32 + q * 8];
          short8 m0h = *(const short8*)&H2h[p2 ^ 1][row * HSTR + q * 8];
          short8 m1h = *(const short8*)&H2h[p2 ^ 1][row * HSTR + 32 + q * 8];
          short8 m0l = *(const short8*)&H2l[p2 ^ 1][row * HSTR + q * 8];
          short8 m1l = *(const short8*)&H2l[p2 ^ 1][row * HSTR + 32 + q * 8];
          floatx4 a0 = bias1v[0], a1 = bias1v[1], a2 = bias1v[2], a3 = bias1v[3];
          // 12 term-major rounds; per-gate order identical to the old chain.
          R4(n0h, B2h[0][0], B2h[1][0], B2h[2][0], B2h[3][0])
          R4(n1h, B2h[0][1], B2h[1][1], B2h[2][1], B2h[3][1])
          R4(n0h, B2l[0][0], B2l[1][0], B2l[2][0], B2l[3][0])
          R4(n1h, B2l[0][1], B2l[1][1], B2l[2][1], B2l[3][1])
          R4(n0l, B2h[0][0], B2h[1][0], B2h[2][0], B2h[3][0])
          R4(n1l, B2h[0][1], B2h[1][1], B2h[2][1], B2h[3][1])
          R4(m0h, B2h[0][2], B2h[1][2], B2h[2][2], B2h[3][2])
          R4(m1h, B2h[0][3], B2h[1][3], B2h[2][3], B2h[3][3])
          R4(m0h, B2l[0][2], B2l[1][2], B2l[2][2], B2l[3][2])
          R4(m1h, B2l[0][3], B2l[1][3], B2l[2][3], B2l[3][3])
          R4(m0l, B2h[0][2], B2h[1][2], B2h[2][2], B2h[3][2])
          R4(m1l, B2h[0][3], B2h[1][3], B2h[2][3], B2h[3][3])
#pragma unroll
          for (int r = 0; r < 4; ++r) {
            float si = sigm2_(a0[r]);
            float sf = sigm2_(a1[r]);
            float tg = tanhg_(a2[r]);
            float so = sigm2_(a3[r]);
            float cc = sf * c2[mt * 4 + r] + si * tg;
            c2[mt * 4 + r] = cc;
            float h = so * tanhc_(cc);
            unsigned u = __float_as_uint(h);
            float hif = __uint_as_float(u & 0xffff0000u);
            unsigned ul = __float_as_uint(h - hif);
            const int m = mt * 16 + q * 4 + r;
            H2h[p2][m * HSTR + j] = (unsigned short)(u >> 16);
            H2l[p2][m * HSTR + j] = (unsigned short)(ul >> 16);
            if (do_out) out[(size_t)(mbase + m) * 320 + (size_t)kk * 64 + j] = h;
          }
        }
      }
      __syncthreads();  // matched with L1 branch
    }
  }
}

#undef R4

extern "C" void kernel_launch(void* const* d_in, const int* in_sizes, int n_in,
                              void* d_out, int out_size, void* d_ws, size_t ws_size,
                              hipStream_t stream) {
  const float* xp   = (const float*)d_in[0];
  const float* Wih0 = (const float*)d_in[1];
  const float* Whh0 = (const float*)d_in[2];
  const float* b0   = (const float*)d_in[3];
  const float* Wih1 = (const float*)d_in[4];
  const float* Whh1 = (const float*)d_in[5];
  const float* b1   = (const float*)d_in[6];
  float* outp = (float*)d_out;
  unsigned short* ws = (unsigned short*)d_ws;

  // Pre-scale + pre-split weights into fragment-ordered hi/lo arrays.
  hipLaunchKernelGGL(prep_weights, dim3(28), dim3(256), 0, stream,
                     Wih0, Whh0, Wih1, Whh1, ws);

  const int B = in_sizes[0] / (T_ * I_);  // 65536
  dim3 grid(B / MB), block(512);
  hipLaunchKernelGGL(lstm2_kernel, grid, block, 0, stream,
                     xp, b0, b1, (const short8*)ws, outp);
}

// Round 9
// 606.830 us; speedup vs baseline: 1.0710x; 1.0710x over previous
//
#include <hip/hip_runtime.h>
#include <hip/hip_bf16.h>

// LSTMEncoder: B=65536, T=25, I=4, H=64, 2 layers, out = h2 at t=4,9,14,19,24.
// Split-precision matmul (v = hi + lo bf16 pairs) for f32-accurate trajectory:
//   h@W ~= h_hi@W_hi + h_hi@W_lo + h_lo@W_hi  (exact products, f32 MFMA acc)
// Elementwise pure f32 (hw exp2/rcp).
//
// R7:  wave specialization (waves 0-3 = layer 1, 4-7 = layer 2), 1 barrier/iter.
// R8:  pre-split weights into d_ws. R9/R10: LDS squeeze; occupancy capped at
//   2 waves/SIMD (weights live in unified VGPR+AGPR, ~200+/wave).
// R11: anti-phase wave scheduling: null. R12: ew VALU cut: null on time.
// R13: term-major MFMA interleave (R4 rounds): -53us -> 522us. BEST.
// R14/R15: MB=128 ILP: spilled (FETCH 14.5->78.5MB), 626us. Reverted.
// R16 (this round): WITHIN-WAVE MFMA/EW OVERLAP at MB=64. R13 counters:
//   MfmaUtil 43% = 304 MFMA x ~17cyc IN-FLIGHT (5.2k) + VALUBusy 52% (6.3k)
//   ~= the whole 12,050 cyc/iter -> the two windows are SEQUENTIAL, even
//   within a wave: one acc set a0..a3 reused per mt forces [MFMA-drain; ew]
//   per tile. Fix: acc double-buffer zA/zB + skewed schedule
//   M(0,A) M(1,B) ew(0,A) M(2,A) ew(1,B) M(3,B) ew(2,A) ew(3,B)
//   so every ew runs while the next tile's MFMAs are in flight. Bias splats
//   -> 4 scalars (offsets the +16 acc regs). Accumulation order unchanged
//   (absmax tripwire: 4.882812e-4).
//
// MFMA 16x16x32 bf16 layouts (measured, learn_hip m89/m120):
//   A[m][k]: m=lane&15, k=(lane>>4)*8+e ; B[k][n]: n=lane&15, k=(lane>>4)*8+e
//   C/D    : col=lane&15, row=(lane>>4)*4+reg

typedef short short8 __attribute__((ext_vector_type(8)));
typedef float floatx4 __attribute__((ext_vector_type(4)));

namespace {
constexpr int T_ = 25;
constexpr int I_ = 4;
constexpr int MB = 64;     // batch rows per block (4 mt-tiles of 16)
constexpr int HSTR = 72;   // LDS row stride (shorts): 144B, 16B-aligned, 2-way banks
constexpr int XSTR = 24;   // x tile stride (shorts): 48B, 2-way banks
constexpr int XPAD = 8;    // last-row overread pad (q=3 reads offs 24..31)

// Workspace layout, in short8 (16B fragment-row) units.
constexpr int OFF_BX   = 0;
constexpr int OFF_HH0H = 1024;
constexpr int OFF_HH0L = 3072;
constexpr int OFF_IH1H = 5120;
constexpr int OFF_IH1L = 7168;
constexpr int OFF_HH1H = 9216;
constexpr int OFF_HH1L = 11264;

constexpr float SC_SIG  = -1.44269504088896340736f;  // -log2(e)
constexpr float SC_TANH = -2.88539008177792681472f;  // -2*log2(e)
}

// Activation helpers. Inputs of sigm2_/tanhg_ are PRE-SCALED via the weights.
__device__ __forceinline__ float sigm2_(float z) {   // z = -log2e * x
  float t = __builtin_amdgcn_exp2f(z);
  return __builtin_amdgcn_rcpf(1.0f + t);
}
__device__ __forceinline__ float tanhg_(float z) {   // z = -2*log2e * x
  float t = __builtin_amdgcn_exp2f(z);
  return 2.0f * __builtin_amdgcn_rcpf(1.0f + t) - 1.0f;
}
__device__ __forceinline__ float tanhc_(float x) {   // plain tanh (c is unscaled)
  float t = __builtin_amdgcn_exp2f(x * SC_TANH);
  return 2.0f * __builtin_amdgcn_rcpf(1.0f + t) - 1.0f;
}

__device__ __forceinline__ unsigned short f2bf_(float f) {  // RNE f32->bf16 (prep only)
  unsigned u = __float_as_uint(f);
  u += 0x7FFFu + ((u >> 16) & 1u);
  return (unsigned short)(u >> 16);
}
__device__ __forceinline__ float bf2f_(unsigned short s) {
  return __uint_as_float(((unsigned)s) << 16);
}
__device__ __forceinline__ void splitf_(float f, unsigned short& hi, unsigned short& lo) {
  hi = f2bf_(f);
  lo = f2bf_(f - bf2f_(hi));
}

// ---------------------------------------------------------------------------
// Prep kernel: scale by activation constants, then split into fragment-ordered
// hi/lo short8 rows. Runs once; RNE split kept here (free).
// ---------------------------------------------------------------------------
__global__ void prep_weights(const float* __restrict__ Wih0,   // [256,4]
                             const float* __restrict__ Whh0,   // [256,64]
                             const float* __restrict__ Wih1,   // [256,64]
                             const float* __restrict__ Whh1,   // [256,64]
                             unsigned short* __restrict__ ws) {
  const int t = blockIdx.x * 256 + threadIdx.x;
  if (t < 1024) {
    const int lane = t & 63, w = (t >> 6) & 3, g = t >> 8;
    const int l = lane & 15, q = lane >> 4;
    const int n = g * 64 + w * 16 + l;
    const float sc = (g == 2) ? SC_TANH : SC_SIG;
    unsigned short row[8];
#pragma unroll
    for (int e = 0; e < 8; ++e) row[e] = 0;
    if (q < 2) {
#pragma unroll
      for (int e = 0; e < 4; ++e) {
        unsigned short h, lo;
        splitf_(Wih0[n * 4 + e] * sc, h, lo);
        row[e] = h;
        if (q == 0) row[4 + e] = lo;
      }
    }
#pragma unroll
    for (int e = 0; e < 8; ++e) ws[(OFF_BX + t) * 8 + e] = row[e];
  } else if (t < 7168) {
    const int a = (t - 1024) >> 11;    // 0:Whh0 1:Wih1 2:Whh1
    const int r = (t - 1024) & 2047;   // r = g*512 + hf*256 + w*64 + lane
    const int lane = r & 63, w = (r >> 6) & 3, hf = (r >> 8) & 1, g = r >> 9;
    const int l = lane & 15, q = lane >> 4;
    const int n = g * 64 + w * 16 + l;
    const float sc = (g == 2) ? SC_TANH : SC_SIG;
    const float* src = (a == 0) ? Whh0 : (a == 1) ? Wih1 : Whh1;
    const int offH = (a == 0) ? OFF_HH0H : (a == 1) ? OFF_IH1H : OFF_HH1H;
    const int offL = offH + 2048;
#pragma unroll
    for (int e = 0; e < 8; ++e) {
      unsigned short h, lo;
      splitf_(src[n * 64 + hf * 32 + q * 8 + e] * sc, h, lo);
      ws[(offH + r) * 8 + e] = h;
      ws[(offL + r) * 8 + e] = lo;
    }
  }
}

// Term-major round: one MFMA from each of the 4 independent gate chains
// (named acc vars). Data deps + the MFMA sched group force round-robin.
#define R4X(z0, z1, z2, z3, A_, b0_, b1_, b2_, b3_)                          \
  z0 = __builtin_amdgcn_mfma_f32_16x16x32_bf16((A_), (b0_), z0, 0, 0, 0);    \
  z1 = __builtin_amdgcn_mfma_f32_16x16x32_bf16((A_), (b1_), z1, 0, 0, 0);    \
  z2 = __builtin_amdgcn_mfma_f32_16x16x32_bf16((A_), (b2_), z2, 0, 0, 0);    \
  z3 = __builtin_amdgcn_mfma_f32_16x16x32_bf16((A_), (b3_), z3, 0, 0, 0);    \
  __builtin_amdgcn_sched_group_barrier(0x008, 4, 0);

// ---------------------------------------------------------------------------
// Main kernel
// ---------------------------------------------------------------------------
__global__ __launch_bounds__(512, 2)
void lstm2_kernel(const float* __restrict__ x,     // [B,25,4]
                  const float* __restrict__ b0,    // [256]
                  const float* __restrict__ b1,    // [256]
                  const short8* __restrict__ wf,   // pre-split scaled weight frags
                  float* __restrict__ out) {       // [B,5,64]
  // h1(t) lives in H1*[t&1]; h2(t) in H2*[t&1]; x(t) in XB[t&1].
  __shared__ __align__(16) unsigned short H1h[2][MB * HSTR];
  __shared__ __align__(16) unsigned short H1l[2][MB * HSTR];
  __shared__ __align__(16) unsigned short H2h[2][MB * HSTR];
  __shared__ __align__(16) unsigned short H2l[2][MB * HSTR];
  __shared__ __align__(16) unsigned short XB[2][MB * XSTR + XPAD];

  const int tid = threadIdx.x;
  const int lane = tid & 63;
  const int w = tid >> 6;   // 0..7
  const int l = lane & 15;
  const int q = lane >> 4;
  const int mbase = blockIdx.x * MB;

  // ---- init LDS: zero the [1] state buffers (h(-1)=0) + both XB buffers ----
  for (int idx = tid; idx < MB * 64; idx += 512) {
    int m = idx >> 6, k = idx & 63;
    H1h[1][m * HSTR + k] = 0;
    H1l[1][m * HSTR + k] = 0;
    H2h[1][m * HSTR + k] = 0;
    H2l[1][m * HSTR + k] = 0;
  }
  for (int idx = tid; idx < 2 * (MB * XSTR + XPAD); idx += 512) (&XB[0][0])[idx] = 0;
  if (tid < 256) {  // stage x(0) into XB[0] (truncation split)
    int m = tid >> 2, ii = tid & 3;
    float xv = x[(mbase + m) * (T_ * I_) + ii];
    unsigned u = __float_as_uint(xv);
    float hif = __uint_as_float(u & 0xffff0000u);
    unsigned ul = __float_as_uint(xv - hif);
    XB[0][m * XSTR + ii] = (unsigned short)(u >> 16);
    XB[0][m * XSTR + 4 + ii] = (unsigned short)(u >> 16);
    XB[0][m * XSTR + 8 + ii] = (unsigned short)(ul >> 16);
  }
  __syncthreads();

  if (w < 4) {
    // ==================== LAYER-1 WAVES (0..3) ====================
    const int j = w * 16 + l;  // hidden col owned (all 4 gates)
    short8 B1h[4][2], B1l[4][2], BXf[4];
    float bb0[4];
#pragma unroll
    for (int g = 0; g < 4; ++g) {
      BXf[g] = wf[OFF_BX + g * 256 + w * 64 + lane];
#pragma unroll
      for (int hf = 0; hf < 2; ++hf) {
        B1h[g][hf] = wf[OFF_HH0H + (g * 2 + hf) * 256 + w * 64 + lane];
        B1l[g][hf] = wf[OFF_HH0L + (g * 2 + hf) * 256 + w * 64 + lane];
      }
      bb0[g] = b0[g * 64 + j] * ((g == 2) ? SC_TANH : SC_SIG);
    }
    float c1[16];
#pragma unroll
    for (int k = 0; k < 16; ++k) c1[k] = 0.f;
    floatx4 zA0, zA1, zA2, zA3, zB0, zB1, zB2, zB3;

#define L1_MFMA(mt_, p_, z0, z1, z2, z3)                                      \
  {                                                                           \
    const int row_ = (mt_) * 16 + l;                                          \
    short8 a0h = *(const short8*)&H1h[(p_) ^ 1][row_ * HSTR + q * 8];         \
    short8 a1h = *(const short8*)&H1h[(p_) ^ 1][row_ * HSTR + 32 + q * 8];    \
    short8 a0l = *(const short8*)&H1l[(p_) ^ 1][row_ * HSTR + q * 8];         \
    short8 a1l = *(const short8*)&H1l[(p_) ^ 1][row_ * HSTR + 32 + q * 8];    \
    short8 ax  = *(const short8*)&XB[p_][row_ * XSTR + q * 8];                \
    z0 = (floatx4){bb0[0], bb0[0], bb0[0], bb0[0]};                           \
    z1 = (floatx4){bb0[1], bb0[1], bb0[1], bb0[1]};                           \
    z2 = (floatx4){bb0[2], bb0[2], bb0[2], bb0[2]};                           \
    z3 = (floatx4){bb0[3], bb0[3], bb0[3], bb0[3]};                           \
    R4X(z0, z1, z2, z3, ax,  BXf[0],    BXf[1],    BXf[2],    BXf[3])         \
    R4X(z0, z1, z2, z3, a0h, B1h[0][0], B1h[1][0], B1h[2][0], B1h[3][0])      \
    R4X(z0, z1, z2, z3, a1h, B1h[0][1], B1h[1][1], B1h[2][1], B1h[3][1])      \
    R4X(z0, z1, z2, z3, a0h, B1l[0][0], B1l[1][0], B1l[2][0], B1l[3][0])      \
    R4X(z0, z1, z2, z3, a1h, B1l[0][1], B1l[1][1], B1l[2][1], B1l[3][1])      \
    R4X(z0, z1, z2, z3, a0l, B1h[0][0], B1h[1][0], B1h[2][0], B1h[3][0])      \
    R4X(z0, z1, z2, z3, a1l, B1h[0][1], B1h[1][1], B1h[2][1], B1h[3][1])      \
  }

#define L1_EW(mt_, p_, z0, z1, z2, z3)                                        \
  {                                                                           \
    _Pragma("unroll")                                                         \
    for (int r = 0; r < 4; ++r) {                                             \
      float si = sigm2_(z0[r]);                                               \
      float sf = sigm2_(z1[r]);                                               \
      float tg = tanhg_(z2[r]);                                               \
      float so = sigm2_(z3[r]);                                               \
      float cc = sf * c1[(mt_) * 4 + r] + si * tg;                            \
      c1[(mt_) * 4 + r] = cc;                                                 \
      float h = so * tanhc_(cc);                                              \
      unsigned u = __float_as_uint(h);                                        \
      float hif = __uint_as_float(u & 0xffff0000u);                           \
      unsigned ul = __float_as_uint(h - hif);                                 \
      const int m_ = (mt_) * 16 + q * 4 + r;                                  \
      H1h[p_][m_ * HSTR + j] = (unsigned short)(u >> 16);                     \
      H1l[p_][m_ * HSTR + j] = (unsigned short)(ul >> 16);                    \
    }                                                                         \
  }

#pragma unroll 1
    for (int tt = 0; tt < T_ + 1; ++tt) {
      if (tt < T_) {
        const int p = tt & 1;  // write h1(tt) -> H1*[p]; read h1(tt-1) <- H1*[p^1]
        // Skewed schedule: every ew overlaps the next tile's in-flight MFMAs.
        L1_MFMA(0, p, zA0, zA1, zA2, zA3)
        L1_MFMA(1, p, zB0, zB1, zB2, zB3)
        L1_EW  (0, p, zA0, zA1, zA2, zA3)
        L1_MFMA(2, p, zA0, zA1, zA2, zA3)
        L1_EW  (1, p, zB0, zB1, zB2, zB3)
        L1_MFMA(3, p, zB0, zB1, zB2, zB3)
        L1_EW  (2, p, zA0, zA1, zA2, zA3)
        L1_EW  (3, p, zB0, zB1, zB2, zB3)
        if (tt + 1 < T_) {  // stage x(tt+1) into the other XB buffer
          int m = (tid & 255) >> 2, ii = tid & 3;
          float xv = x[(mbase + m) * (T_ * I_) + (tt + 1) * I_ + ii];
          unsigned u = __float_as_uint(xv);
          float hif = __uint_as_float(u & 0xffff0000u);
          unsigned ul = __float_as_uint(xv - hif);
          XB[(tt + 1) & 1][m * XSTR + ii] = (unsigned short)(u >> 16);
          XB[(tt + 1) & 1][m * XSTR + 4 + ii] = (unsigned short)(u >> 16);
          XB[(tt + 1) & 1][m * XSTR + 8 + ii] = (unsigned short)(ul >> 16);
        }
      }
      __syncthreads();  // barrier 1-per-iter, matched with L2 branch
    }
#undef L1_MFMA
#undef L1_EW
  } else {
    // ==================== LAYER-2 WAVES (4..7) ====================
    const int w2 = w - 4;
    const int j = w2 * 16 + l;
    short8 B2h[4][4], B2l[4][4];  // [0..1]=Wih1, [2..3]=Whh1
    float bb1[4];
#pragma unroll
    for (int g = 0; g < 4; ++g) {
#pragma unroll
      for (int hf = 0; hf < 2; ++hf) {
        B2h[g][hf]     = wf[OFF_IH1H + (g * 2 + hf) * 256 + w2 * 64 + lane];
        B2l[g][hf]     = wf[OFF_IH1L + (g * 2 + hf) * 256 + w2 * 64 + lane];
        B2h[g][2 + hf] = wf[OFF_HH1H + (g * 2 + hf) * 256 + w2 * 64 + lane];
        B2l[g][2 + hf] = wf[OFF_HH1L + (g * 2 + hf) * 256 + w2 * 64 + lane];
      }
      bb1[g] = b1[g * 64 + j] * ((g == 2) ? SC_TANH : SC_SIG);
    }
    float c2[16];
#pragma unroll
    for (int k = 0; k < 16; ++k) c2[k] = 0.f;
    floatx4 zA0, zA1, zA2, zA3, zB0, zB1, zB2, zB3;

#define L2_MFMA(mt_, p2_, z0, z1, z2, z3)                                     \
  {                                                                           \
    const int row_ = (mt_) * 16 + l;                                          \
    short8 n0h = *(const short8*)&H1h[p2_][row_ * HSTR + q * 8];              \
    short8 n1h = *(const short8*)&H1h[p2_][row_ * HSTR + 32 + q * 8];         \
    short8 n0l = *(const short8*)&H1l[p2_][row_ * HSTR + q * 8];              \
    short8 n1l = *(const short8*)&H1l[p2_][row_ * HSTR + 32 + q * 8];         \
    short8 m0h = *(const short8*)&H2h[(p2_) ^ 1][row_ * HSTR + q * 8];        \
    short8 m1h = *(const short8*)&H2h[(p2_) ^ 1][row_ * HSTR + 32 + q * 8];   \
    short8 m0l = *(const short8*)&H2l[(p2_) ^ 1][row_ * HSTR + q * 8];        \
    short8 m1l = *(const short8*)&H2l[(p2_) ^ 1][row_ * HSTR + 32 + q * 8];   \
    z0 = (floatx4){bb1[0], bb1[0], bb1[0], bb1[0]};                           \
    z1 = (floatx4){bb1[1], bb1[1], bb1[1], bb1[1]};                           \
    z2 = (floatx4){bb1[2], bb1[2], bb1[2], bb1[2]};                           \
    z3 = (floatx4){bb1[3], bb1[3], bb1[3], bb1[3]};                           \
    R4X(z0, z1, z2, z3, n0h, B2h[0][0], B2h[1][0], B2h[2][0], B2h[3][0])      \
    R4X(z0, z1, z2, z3, n1h, B2h[0][1], B2h[1][1], B2h[2][1], B2h[3][1])      \
    R4X(z0, z1, z2, z3, n0h, B2l[0][0], B2l[1][0], B2l[2][0], B2l[3][0])      \
    R4X(z0, z1, z2, z3, n1h, B2l[0][1], B2l[1][1], B2l[2][1], B2l[3][1])      \
    R4X(z0, z1, z2, z3, n0l, B2h[0][0], B2h[1][0], B2h[2][0], B2h[3][0])      \
    R4X(z0, z1, z2, z3, n1l, B2h[0][1], B2h[1][1], B2h[2][1], B2h[3][1])      \
    R4X(z0, z1, z2, z3, m0h, B2h[0][2], B2h[1][2], B2h[2][2], B2h[3][2])      \
    R4X(z0, z1, z2, z3, m1h, B2h[0][3], B2h[1][3], B2h[2][3], B2h[3][3])      \
    R4X(z0, z1, z2, z3, m0h, B2l[0][2], B2l[1][2], B2l[2][2], B2l[3][2])      \
    R4X(z0, z1, z2, z3, m1h, B2l[0][3], B2l[1][3], B2l[2][3], B2l[3][3])      \
    R4X(z0, z1, z2, z3, m0l, B2h[0][2], B2h[1][2], B2h[2][2], B2h[3][2])      \
    R4X(z0, z1, z2, z3, m1l, B2h[0][3], B2h[1][3], B2h[2][3], B2h[3][3])      \
  }

#define L2_EW(mt_, t2_, z0, z1, z2, z3)                                       \
  {                                                                           \
    const int p2_ = (t2_) & 1;                                                \
    const bool do_out_ = ((t2_) % 5 == 4);                                    \
    const int kk_ = (t2_) / 5;                                                \
    _Pragma("unroll")                                                         \
    for (int r = 0; r < 4; ++r) {                                             \
      float si = sigm2_(z0[r]);                                               \
      float sf = sigm2_(z1[r]);                                               \
      float tg = tanhg_(z2[r]);                                               \
      float so = sigm2_(z3[r]);                                               \
      float cc = sf * c2[(mt_) * 4 + r] + si * tg;                            \
      c2[(mt_) * 4 + r] = cc;                                                 \
      float h = so * tanhc_(cc);                                              \
      unsigned u = __float_as_uint(h);                                        \
      float hif = __uint_as_float(u & 0xffff0000u);                           \
      unsigned ul = __float_as_uint(h - hif);                                 \
      const int m_ = (mt_) * 16 + q * 4 + r;                                  \
      H2h[p2_][m_ * HSTR + j] = (unsigned short)(u >> 16);                    \
      H2l[p2_][m_ * HSTR + j] = (unsigned short)(ul >> 16);                   \
      if (do_out_) out[(size_t)(mbase + m_) * 320 + (size_t)kk_ * 64 + j] = h;\
    }                                                                         \
  }

#pragma unroll 1
    for (int tt = 0; tt < T_ + 1; ++tt) {
      if (tt >= 1) {
        const int t2 = tt - 1;   // computing h2(t2)
        const int p2 = t2 & 1;   // read h1(t2) <- H1*[p2], h2(t2-1) <- H2*[p2^1]
        L2_MFMA(0, p2, zA0, zA1, zA2, zA3)
        L2_MFMA(1, p2, zB0, zB1, zB2, zB3)
        L2_EW  (0, t2, zA0, zA1, zA2, zA3)
        L2_MFMA(2, p2, zA0, zA1, zA2, zA3)
        L2_EW  (1, t2, zB0, zB1, zB2, zB3)
        L2_MFMA(3, p2, zB0, zB1, zB2, zB3)
        L2_EW  (2, t2, zA0, zA1, zA2, zA3)
        L2_EW  (3, t2, zB0, zB1, zB2, zB3)
      }
      __syncthreads();  // matched with L1 branch
    }
#undef L2_MFMA
#undef L2_EW
  }
}

#undef R4X

extern "C" void kernel_launch(void* const* d_in, const int* in_sizes, int n_in,
                              void* d_out, int out_size, void* d_ws, size_t ws_size,
                              hipStream_t stream) {
  const float* xp   = (const float*)d_in[0];
  const float* Wih0 = (const float*)d_in[1];
  const float* Whh0 = (const float*)d_in[2];
  const float* b0   = (const float*)d_in[3];
  const float* Wih1 = (const float*)d_in[4];
  const float* Whh1 = (const float*)d_in[5];
  const float* b1   = (const float*)d_in[6];
  float* outp = (float*)d_out;
  unsigned short* ws = (unsigned short*)d_ws;

  // Pre-scale + pre-split weights into fragment-ordered hi/lo arrays.
  hipLaunchKernelGGL(prep_weights, dim3(28), dim3(256), 0, stream,
                     Wih0, Whh0, Wih1, Whh1, ws);

  const int B = in_sizes[0] / (T_ * I_);  // 65536
  dim3 grid(B / MB), block(512);
  hipLaunchKernelGGL(lstm2_kernel, grid, block, 0, stream,
                     xp, b0, b1, (const short8*)ws, outp);
}

// Round 10
// 496.417 us; speedup vs baseline: 1.3092x; 1.2224x over previous
//
#include <hip/hip_runtime.h>
#include <hip/hip_fp16.h>

// LSTMEncoder: B=65536, T=25, I=4, H=64, 2 layers, out = h2 at t=4,9,14,19,24.
// R17: FP16 SPLIT-PRECISION (2-term) replaces bf16 3-term.
//   Arithmetic: per-SIMD 16x16x32 MFMA occupancy is ~16-19 cyc (m06 ceiling
//   422 MAC/cyc/SIMD), so R13's 304 MFMAs/SIMD/iter = ~4,900 cyc = MfmaUtil
//   40% -> compute-bound on 3x-redundant split math. fp16 h (2^-12 rel err,
//   vs bf16 2^-9 which failed at 1.15e-2 -> predicts ~1.4e-3 final, under
//   the 2.97e-3 threshold) + W = W_hi + W_lo*2^-11 with W_lo PRE-SCALED by
//   2^11 (raw W_lo <= 4.4e-5 is fp16-subnormal; scaled ~0.09 normal; the
//   2^-11 is restored in f32 at accumulator fold - exact). MFMA 304->224,
//   h-LDS halves (~39KB/block -> 2 blocks/CU at the 128-VGPR cap -> 4
//   waves/SIMD), ew split 4 ops -> 1 cvt, ds_writes halve.
// History: R7 wave-spec; R8 pre-split ws; R9/R10 LDS squeeze (occupancy was
//   reg-capped); R11 anti-phase null; R12 ew cut null; R13 term-major MFMA
//   rounds -53us (522, best); R14/15 MB=128 spilled; R16 acc-dbuf spilled.
//
// MFMA 16x16x32 layouts (learn_hip m89/m120, dtype-independent C/D):
//   A[m][k]: m=lane&15, k=(lane>>4)*8+e ; B[k][n]: n=lane&15, k=(lane>>4)*8+e
//   C/D    : col=lane&15, row=(lane>>4)*4+reg

typedef _Float16 half8 __attribute__((ext_vector_type(8)));
typedef float floatx4 __attribute__((ext_vector_type(4)));

namespace {
constexpr int T_ = 25;
constexpr int I_ = 4;
constexpr int MB = 64;     // batch rows per block (4 mt-tiles of 16)
constexpr int HSTR = 72;   // H LDS row stride (halves): 144B, 2-way-bank b128 reads
constexpr int XSTR = 8;    // x row stride (halves): 16B; q>=1 reads garbage x B-zero
constexpr int XPAD = 24;   // last-row overread pad (q=3 reads up to +31 halves)

// Workspace layout, in half8 (16B fragment-row) units.
constexpr int OFF_BXH  = 0;      // Wih0 hi   [g][w][lane], q==0 rows only
constexpr int OFF_BXL  = 1024;   // Wih0 lo*2^11
constexpr int OFF_HH0H = 2048;   // Whh0 hi   [g][hf][w][lane]
constexpr int OFF_HH0L = 4096;   // Whh0 lo*2^11
constexpr int OFF_IH1H = 6144;
constexpr int OFF_IH1L = 8192;
constexpr int OFF_HH1H = 10240;
constexpr int OFF_HH1L = 12288;  // end 14336 rows * 16B = 229,376 B of d_ws

constexpr float SC_SIG   = -1.44269504088896340736f;  // -log2(e)
constexpr float SC_TANH  = -2.88539008177792681472f;  // -2*log2(e)
constexpr float LO_INV   = 0.00048828125f;            // 2^-11 fold factor
}

// Activation helpers; matmul inputs are PRE-SCALED via the weights.
__device__ __forceinline__ float sigm2_(float z) {   // z = -log2e * x
  float t = __builtin_amdgcn_exp2f(z);
  return __builtin_amdgcn_rcpf(1.0f + t);
}
__device__ __forceinline__ float tanhg_(float z) {   // z = -2*log2e * x
  float t = __builtin_amdgcn_exp2f(z);
  return 2.0f * __builtin_amdgcn_rcpf(1.0f + t) - 1.0f;
}
__device__ __forceinline__ float tanhc_(float x) {   // plain tanh (c unscaled)
  float t = __builtin_amdgcn_exp2f(x * SC_TANH);
  return 2.0f * __builtin_amdgcn_rcpf(1.0f + t) - 1.0f;
}

__device__ __forceinline__ unsigned short f2h_(float f) {  // RNE f32->f16
  _Float16 h = (_Float16)f;
  unsigned short u;
  __builtin_memcpy(&u, &h, 2);
  return u;
}
__device__ __forceinline__ float h2f_(unsigned short u) {
  _Float16 h;
  __builtin_memcpy(&h, &u, 2);
  return (float)h;
}

// ---------------------------------------------------------------------------
// Prep kernel: scale by activation constants, fp16-split (hi + lo*2^11) into
// fragment-ordered half8 rows. 8192 threads, runs once.
// ---------------------------------------------------------------------------
__global__ void prep_weights(const float* __restrict__ Wih0,   // [256,4]
                             const float* __restrict__ Whh0,   // [256,64]
                             const float* __restrict__ Wih1,   // [256,64]
                             const float* __restrict__ Whh1,   // [256,64]
                             unsigned short* __restrict__ ws) {
  const int t = blockIdx.x * 256 + threadIdx.x;
  if (t < 2048) {
    // BXH rows 0..1023, BXL rows 1024..2047 (same index math, OFF_BXH=0).
    const int t2 = t & 1023;
    const int lane = t2 & 63, w = (t2 >> 6) & 3, g = t2 >> 8;
    const int l = lane & 15, q = lane >> 4;
    const int n = g * 64 + w * 16 + l;
    const float sc = (g == 2) ? SC_TANH : SC_SIG;
    unsigned short row[8];
#pragma unroll
    for (int e = 0; e < 8; ++e) row[e] = 0;
    if (q == 0) {
#pragma unroll
      for (int e = 0; e < 4; ++e) {
        float wv = Wih0[n * 4 + e] * sc;
        unsigned short hi = f2h_(wv);
        unsigned short lo = f2h_((wv - h2f_(hi)) * 2048.0f);
        row[e] = (t < 1024) ? hi : lo;
      }
    }
#pragma unroll
    for (int e = 0; e < 8; ++e) ws[t * 8 + e] = row[e];
  } else if (t < 8192) {
    const int idx = t - 2048;          // 0..6143
    const int a = idx >> 11;           // 0:Whh0 1:Wih1 2:Whh1
    const int r = idx & 2047;          // g*512 + hf*256 + w*64 + lane
    const int lane = r & 63, w = (r >> 6) & 3, hf = (r >> 8) & 1, g = r >> 9;
    const int l = lane & 15, q = lane >> 4;
    const int n = g * 64 + w * 16 + l;
    const float sc = (g == 2) ? SC_TANH : SC_SIG;
    const float* src = (a == 0) ? Whh0 : (a == 1) ? Wih1 : Whh1;
    const int offH = (a == 0) ? OFF_HH0H : (a == 1) ? OFF_IH1H : OFF_HH1H;
    const int offL = offH + 2048;
#pragma unroll
    for (int e = 0; e < 8; ++e) {
      float wv = src[n * 64 + hf * 32 + q * 8 + e] * sc;
      unsigned short hi = f2h_(wv);
      unsigned short lo = f2h_((wv - h2f_(hi)) * 2048.0f);
      ws[(offH + r) * 8 + e] = hi;
      ws[(offL + r) * 8 + e] = lo;
    }
  }
}

// Term-major round into a named acc set: one MFMA per gate chain, round-robin
// enforced by data deps + MFMA sched group (R13, proven).
#define R4X(z0, z1, z2, z3, A_, b0_, b1_, b2_, b3_)                          \
  z0 = __builtin_amdgcn_mfma_f32_16x16x32_f16((A_), (b0_), z0, 0, 0, 0);     \
  z1 = __builtin_amdgcn_mfma_f32_16x16x32_f16((A_), (b1_), z1, 0, 0, 0);     \
  z2 = __builtin_amdgcn_mfma_f32_16x16x32_f16((A_), (b2_), z2, 0, 0, 0);     \
  z3 = __builtin_amdgcn_mfma_f32_16x16x32_f16((A_), (b3_), z3, 0, 0, 0);     \
  __builtin_amdgcn_sched_group_barrier(0x008, 4, 0);

// ---------------------------------------------------------------------------
// Main kernel
// ---------------------------------------------------------------------------
__global__ __launch_bounds__(512, 2)
void lstm2_kernel(const float* __restrict__ x,     // [B,25,4]
                  const float* __restrict__ b0,    // [256]
                  const float* __restrict__ b1,    // [256]
                  const half8* __restrict__ wf,    // pre-split fp16 weight frags
                  float* __restrict__ out) {       // [B,5,64]
  // h1(t) lives in H1[t&1]; h2(t) in H2[t&1]; x(t) in XB[t&1]. All fp16.
  __shared__ __align__(16) unsigned short H1[2][MB * HSTR];
  __shared__ __align__(16) unsigned short H2[2][MB * HSTR];
  __shared__ __align__(16) unsigned short XB[2][MB * XSTR + XPAD];

  const int tid = threadIdx.x;
  const int lane = tid & 63;
  const int w = tid >> 6;   // 0..7
  const int l = lane & 15;
  const int q = lane >> 4;
  const int mbase = blockIdx.x * MB;

  // ---- init LDS: zero [1] state buffers (h(-1)=0) + both XB buffers ----
  for (int idx = tid; idx < MB * 64; idx += 512) {
    int m = idx >> 6, k = idx & 63;
    H1[1][m * HSTR + k] = 0;
    H2[1][m * HSTR + k] = 0;
  }
  for (int idx = tid; idx < 2 * (MB * XSTR + XPAD); idx += 512) (&XB[0][0])[idx] = 0;
  if (tid < 256) {  // stage x(0)
    int m = tid >> 2, ii = tid & 3;
    XB[0][m * XSTR + ii] = f2h_(x[(mbase + m) * (T_ * I_) + ii]);
  }
  __syncthreads();

  if (w < 4) {
    // ==================== LAYER-1 WAVES (0..3) ====================
    const int j = w * 16 + l;  // hidden col owned (all 4 gates)
    half8 BXH[4], BXL[4], WH[4][2], WL[4][2];
    float bb0[4];
#pragma unroll
    for (int g = 0; g < 4; ++g) {
      BXH[g] = wf[OFF_BXH + g * 256 + w * 64 + lane];
      BXL[g] = wf[OFF_BXL + g * 256 + w * 64 + lane];
#pragma unroll
      for (int hf = 0; hf < 2; ++hf) {
        WH[g][hf] = wf[OFF_HH0H + (g * 2 + hf) * 256 + w * 64 + lane];
        WL[g][hf] = wf[OFF_HH0L + (g * 2 + hf) * 256 + w * 64 + lane];
      }
      bb0[g] = b0[g * 64 + j] * ((g == 2) ? SC_TANH : SC_SIG);
    }
    float c1[16];
#pragma unroll
    for (int k = 0; k < 16; ++k) c1[k] = 0.f;

#pragma unroll 1
    for (int tt = 0; tt < T_ + 1; ++tt) {
      if (tt < T_) {
        const int p = tt & 1;  // write h1(tt) -> H1[p]; read h1(tt-1) <- H1[p^1]
#pragma unroll
        for (int mt = 0; mt < 4; ++mt) {
          const int row = mt * 16 + l;
          half8 ah0 = *(const half8*)&H1[p ^ 1][row * HSTR + q * 8];
          half8 ah1 = *(const half8*)&H1[p ^ 1][row * HSTR + 32 + q * 8];
          half8 ax  = *(const half8*)&XB[p][row * XSTR + q * 8];
          floatx4 zm0 = {bb0[0], bb0[0], bb0[0], bb0[0]};
          floatx4 zm1 = {bb0[1], bb0[1], bb0[1], bb0[1]};
          floatx4 zm2 = {bb0[2], bb0[2], bb0[2], bb0[2]};
          floatx4 zm3 = {bb0[3], bb0[3], bb0[3], bb0[3]};
          floatx4 zl0 = {0.f, 0.f, 0.f, 0.f}, zl1 = zl0, zl2 = zl0, zl3 = zl0;
          // Interleaved zm/zl rounds: same-chain spacing = 8 MFMAs.
          R4X(zm0, zm1, zm2, zm3, ax,  BXH[0],   BXH[1],   BXH[2],   BXH[3])
          R4X(zl0, zl1, zl2, zl3, ax,  BXL[0],   BXL[1],   BXL[2],   BXL[3])
          R4X(zm0, zm1, zm2, zm3, ah0, WH[0][0], WH[1][0], WH[2][0], WH[3][0])
          R4X(zl0, zl1, zl2, zl3, ah0, WL[0][0], WL[1][0], WL[2][0], WL[3][0])
          R4X(zm0, zm1, zm2, zm3, ah1, WH[0][1], WH[1][1], WH[2][1], WH[3][1])
          R4X(zl0, zl1, zl2, zl3, ah1, WL[0][1], WL[1][1], WL[2][1], WL[3][1])
          floatx4 z0 = zm0 + zl0 * LO_INV;
          floatx4 z1 = zm1 + zl1 * LO_INV;
          floatx4 z2 = zm2 + zl2 * LO_INV;
          floatx4 z3 = zm3 + zl3 * LO_INV;
#pragma unroll
          for (int r = 0; r < 4; ++r) {
            float si = sigm2_(z0[r]);
            float sf = sigm2_(z1[r]);
            float tg = tanhg_(z2[r]);
            float so = sigm2_(z3[r]);
            float cc = sf * c1[mt * 4 + r] + si * tg;
            c1[mt * 4 + r] = cc;
            float h = so * tanhc_(cc);
            const int m = mt * 16 + q * 4 + r;
            H1[p][m * HSTR + j] = f2h_(h);
          }
        }
        if (tt + 1 < T_) {  // stage x(tt+1) into the other XB buffer
          int m = (tid & 255) >> 2, ii = tid & 3;
          XB[(tt + 1) & 1][m * XSTR + ii] =
              f2h_(x[(mbase + m) * (T_ * I_) + (tt + 1) * I_ + ii]);
        }
      }
      __syncthreads();  // barrier 1-per-iter, matched with L2 branch
    }
  } else {
    // ==================== LAYER-2 WAVES (4..7) ====================
    const int w2 = w - 4;
    const int j = w2 * 16 + l;
    half8 IH[4][2], IL[4][2], GH[4][2], GL[4][2];  // ih hi/lo, hh hi/lo
    float bb1[4];
#pragma unroll
    for (int g = 0; g < 4; ++g) {
#pragma unroll
      for (int hf = 0; hf < 2; ++hf) {
        IH[g][hf] = wf[OFF_IH1H + (g * 2 + hf) * 256 + w2 * 64 + lane];
        IL[g][hf] = wf[OFF_IH1L + (g * 2 + hf) * 256 + w2 * 64 + lane];
        GH[g][hf] = wf[OFF_HH1H + (g * 2 + hf) * 256 + w2 * 64 + lane];
        GL[g][hf] = wf[OFF_HH1L + (g * 2 + hf) * 256 + w2 * 64 + lane];
      }
      bb1[g] = b1[g * 64 + j] * ((g == 2) ? SC_TANH : SC_SIG);
    }
    float c2[16];
#pragma unroll
    for (int k = 0; k < 16; ++k) c2[k] = 0.f;

#pragma unroll 1
    for (int tt = 0; tt < T_ + 1; ++tt) {
      if (tt >= 1) {
        const int t2 = tt - 1;   // computing h2(t2)
        const int p2 = t2 & 1;   // read h1(t2) <- H1[p2], h2(t2-1) <- H2[p2^1]
        const bool do_out = (t2 % 5 == 4);
        const int kk = t2 / 5;
#pragma unroll
        for (int mt = 0; mt < 4; ++mt) {
          const int row = mt * 16 + l;
          half8 nh0 = *(const half8*)&H1[p2][row * HSTR + q * 8];
          half8 nh1 = *(const half8*)&H1[p2][row * HSTR + 32 + q * 8];
          half8 mh0 = *(const half8*)&H2[p2 ^ 1][row * HSTR + q * 8];
          half8 mh1 = *(const half8*)&H2[p2 ^ 1][row * HSTR + 32 + q * 8];
          floatx4 zm0 = {bb1[0], bb1[0], bb1[0], bb1[0]};
          floatx4 zm1 = {bb1[1], bb1[1], bb1[1], bb1[1]};
          floatx4 zm2 = {bb1[2], bb1[2], bb1[2], bb1[2]};
          floatx4 zm3 = {bb1[3], bb1[3], bb1[3], bb1[3]};
          floatx4 zl0 = {0.f, 0.f, 0.f, 0.f}, zl1 = zl0, zl2 = zl0, zl3 = zl0;
          R4X(zm0, zm1, zm2, zm3, nh0, IH[0][0], IH[1][0], IH[2][0], IH[3][0])
          R4X(zl0, zl1, zl2, zl3, nh0, IL[0][0], IL[1][0], IL[2][0], IL[3][0])
          R4X(zm0, zm1, zm2, zm3, nh1, IH[0][1], IH[1][1], IH[2][1], IH[3][1])
          R4X(zl0, zl1, zl2, zl3, nh1, IL[0][1], IL[1][1], IL[2][1], IL[3][1])
          R4X(zm0, zm1, zm2, zm3, mh0, GH[0][0], GH[1][0], GH[2][0], GH[3][0])
          R4X(zl0, zl1, zl2, zl3, mh0, GL[0][0], GL[1][0], GL[2][0], GL[3][0])
          R4X(zm0, zm1, zm2, zm3, mh1, GH[0][1], GH[1][1], GH[2][1], GH[3][1])
          R4X(zl0, zl1, zl2, zl3, mh1, GL[0][1], GL[1][1], GL[2][1], GL[3][1])
          floatx4 z0 = zm0 + zl0 * LO_INV;
          floatx4 z1 = zm1 + zl1 * LO_INV;
          floatx4 z2 = zm2 + zl2 * LO_INV;
          floatx4 z3 = zm3 + zl3 * LO_INV;
#pragma unroll
          for (int r = 0; r < 4; ++r) {
            float si = sigm2_(z0[r]);
            float sf = sigm2_(z1[r]);
            float tg = tanhg_(z2[r]);
            float so = sigm2_(z3[r]);
            float cc = sf * c2[mt * 4 + r] + si * tg;
            c2[mt * 4 + r] = cc;
            float h = so * tanhc_(cc);
            const int m = mt * 16 + q * 4 + r;
            H2[p2][m * HSTR + j] = f2h_(h);
            if (do_out) out[(size_t)(mbase + m) * 320 + (size_t)kk * 64 + j] = h;
          }
        }
      }
      __syncthreads();  // matched with L1 branch
    }
  }
}

#undef R4X

extern "C" void kernel_launch(void* const* d_in, const int* in_sizes, int n_in,
                              void* d_out, int out_size, void* d_ws, size_t ws_size,
                              hipStream_t stream) {
  const float* xp   = (const float*)d_in[0];
  const float* Wih0 = (const float*)d_in[1];
  const float* Whh0 = (const float*)d_in[2];
  const float* b0   = (const float*)d_in[3];
  const float* Wih1 = (const float*)d_in[4];
  const float* Whh1 = (const float*)d_in[5];
  const float* b1   = (const float*)d_in[6];
  float* outp = (float*)d_out;
  unsigned short* ws = (unsigned short*)d_ws;

  // Pre-scale + fp16-split weights into fragment-ordered hi / lo*2^11 arrays.
  hipLaunchKernelGGL(prep_weights, dim3(32), dim3(256), 0, stream,
                     Wih0, Whh0, Wih1, Whh1, ws);

  const int B = in_sizes[0] / (T_ * I_);  // 65536
  dim3 grid(B / MB), block(512);
  hipLaunchKernelGGL(lstm2_kernel, grid, block, 0, stream,
                     xp, b0, b1, (const half8*)ws, outp);
}

// Round 11
// 396.050 us; speedup vs baseline: 1.6410x; 1.2534x over previous
//
#include <hip/hip_runtime.h>
#include <hip/hip_fp16.h>

// LSTMEncoder: B=65536, T=25, I=4, H=64, 2 layers, out = h2 at t=4,9,14,19,24.
// R18: PURE FP16 WEIGHTS (drop the lo split term).
//   R17 (fp16 2-term split) = 467us, absmax 9.77e-4, but Occupancy stayed 23%:
//   true per-wave reg total (unified VGPR+acc) > the reported 128 -> still
//   register-gated at 2 waves/SIMD; L2's 32 weight frags = 128 regs alone.
//   Error budget: measured 9.77e-4 already includes h-quant (2^-11) and
//   x-quant (2^-12, single-fp16 x since R17). W-quant at 2^-12 relative is
//   the same order -> predicted final ~1.5-2e-3 < 2.97e-3 threshold. (The
//   "16-bit matmul fails" history was bf16 at 2^-8; fp16 is 8x finer.)
//   Wins: MFMA 224->112/SIMD-iter; L2 weight regs 128->64, L1 96->48 ->
//   total/wave ~105-120 <= 128 -> 4 waves/SIMD -> 2 blocks/CU at last;
//   acc fold removed. Keep launch_bounds(512,2) (=128-reg cap, proven),
//   R13 term-major rounds, R17 structure otherwise.
// History: R7 wave-spec; R8 pre-split ws; R9/R10 LDS squeeze; R11 anti-phase
//   null; R12 ew cut null; R13 term-major -53us; R14/15 MB=128 spill;
//   R16 acc-dbuf spill; R17 fp16 split -55us (467).
//
// MFMA 16x16x32 layouts (learn_hip m89/m120, dtype-independent C/D):
//   A[m][k]: m=lane&15, k=(lane>>4)*8+e ; B[k][n]: n=lane&15, k=(lane>>4)*8+e
//   C/D    : col=lane&15, row=(lane>>4)*4+reg

typedef _Float16 half8 __attribute__((ext_vector_type(8)));
typedef float floatx4 __attribute__((ext_vector_type(4)));

namespace {
constexpr int T_ = 25;
constexpr int I_ = 4;
constexpr int MB = 64;     // batch rows per block (4 mt-tiles of 16)
constexpr int HSTR = 72;   // H LDS row stride (halves): 144B, 2-way-bank b128 reads
constexpr int XSTR = 8;    // x row stride (halves): 16B; q>=1 reads garbage x B-zero
constexpr int XPAD = 24;   // last-row overread pad (q=3 reads up to +31 halves)

// Workspace layout, in half8 (16B fragment-row) units. Single fp16 per weight.
constexpr int OFF_BX  = 0;      // Wih0 [g][w][lane], q==0 rows only: 1024 rows
constexpr int OFF_HH0 = 1024;   // Whh0 [g][hf][w][lane]: 2048 rows
constexpr int OFF_IH1 = 3072;   // Wih1: 2048 rows
constexpr int OFF_HH1 = 5120;   // Whh1: 2048 rows -> 7168 rows * 16B = 114,688 B

constexpr float SC_SIG   = -1.44269504088896340736f;  // -log2(e)
constexpr float SC_TANH  = -2.88539008177792681472f;  // -2*log2(e)
}

// Activation helpers; matmul inputs are PRE-SCALED via the weights.
__device__ __forceinline__ float sigm2_(float z) {   // z = -log2e * x
  float t = __builtin_amdgcn_exp2f(z);
  return __builtin_amdgcn_rcpf(1.0f + t);
}
__device__ __forceinline__ float tanhg_(float z) {   // z = -2*log2e * x
  float t = __builtin_amdgcn_exp2f(z);
  return 2.0f * __builtin_amdgcn_rcpf(1.0f + t) - 1.0f;
}
__device__ __forceinline__ float tanhc_(float x) {   // plain tanh (c unscaled)
  float t = __builtin_amdgcn_exp2f(x * SC_TANH);
  return 2.0f * __builtin_amdgcn_rcpf(1.0f + t) - 1.0f;
}

__device__ __forceinline__ unsigned short f2h_(float f) {  // RNE f32->f16
  _Float16 h = (_Float16)f;
  unsigned short u;
  __builtin_memcpy(&u, &h, 2);
  return u;
}

// ---------------------------------------------------------------------------
// Prep kernel: scale by activation constants, fp16-round into fragment-ordered
// half8 rows. 7168 threads, runs once.
// ---------------------------------------------------------------------------
__global__ void prep_weights(const float* __restrict__ Wih0,   // [256,4]
                             const float* __restrict__ Whh0,   // [256,64]
                             const float* __restrict__ Wih1,   // [256,64]
                             const float* __restrict__ Whh1,   // [256,64]
                             unsigned short* __restrict__ ws) {
  const int t = blockIdx.x * 256 + threadIdx.x;
  if (t < 1024) {
    const int lane = t & 63, w = (t >> 6) & 3, g = t >> 8;
    const int l = lane & 15, q = lane >> 4;
    const int n = g * 64 + w * 16 + l;
    const float sc = (g == 2) ? SC_TANH : SC_SIG;
    unsigned short row[8];
#pragma unroll
    for (int e = 0; e < 8; ++e) row[e] = 0;
    if (q == 0) {
#pragma unroll
      for (int e = 0; e < 4; ++e) row[e] = f2h_(Wih0[n * 4 + e] * sc);
    }
#pragma unroll
    for (int e = 0; e < 8; ++e) ws[t * 8 + e] = row[e];
  } else if (t < 7168) {
    const int idx = t - 1024;          // 0..6143
    const int a = idx >> 11;           // 0:Whh0 1:Wih1 2:Whh1
    const int r = idx & 2047;          // g*512 + hf*256 + w*64 + lane
    const int lane = r & 63, w = (r >> 6) & 3, hf = (r >> 8) & 1, g = r >> 9;
    const int l = lane & 15, q = lane >> 4;
    const int n = g * 64 + w * 16 + l;
    const float sc = (g == 2) ? SC_TANH : SC_SIG;
    const float* src = (a == 0) ? Whh0 : (a == 1) ? Wih1 : Whh1;
    const int off = (a == 0) ? OFF_HH0 : (a == 1) ? OFF_IH1 : OFF_HH1;
#pragma unroll
    for (int e = 0; e < 8; ++e)
      ws[(off + r) * 8 + e] = f2h_(src[n * 64 + hf * 32 + q * 8 + e] * sc);
  }
}

// Term-major round: one MFMA per gate chain, round-robin enforced by data
// deps + MFMA sched group (R13, proven).
#define R4X(z0, z1, z2, z3, A_, b0_, b1_, b2_, b3_)                          \
  z0 = __builtin_amdgcn_mfma_f32_16x16x32_f16((A_), (b0_), z0, 0, 0, 0);     \
  z1 = __builtin_amdgcn_mfma_f32_16x16x32_f16((A_), (b1_), z1, 0, 0, 0);     \
  z2 = __builtin_amdgcn_mfma_f32_16x16x32_f16((A_), (b2_), z2, 0, 0, 0);     \
  z3 = __builtin_amdgcn_mfma_f32_16x16x32_f16((A_), (b3_), z3, 0, 0, 0);     \
  __builtin_amdgcn_sched_group_barrier(0x008, 4, 0);

// ---------------------------------------------------------------------------
// Main kernel
// ---------------------------------------------------------------------------
__global__ __launch_bounds__(512, 2)
void lstm2_kernel(const float* __restrict__ x,     // [B,25,4]
                  const float* __restrict__ b0,    // [256]
                  const float* __restrict__ b1,    // [256]
                  const half8* __restrict__ wf,    // fp16 weight frags
                  float* __restrict__ out) {       // [B,5,64]
  // h1(t) lives in H1[t&1]; h2(t) in H2[t&1]; x(t) in XB[t&1]. All fp16.
  __shared__ __align__(16) unsigned short H1[2][MB * HSTR];
  __shared__ __align__(16) unsigned short H2[2][MB * HSTR];
  __shared__ __align__(16) unsigned short XB[2][MB * XSTR + XPAD];

  const int tid = threadIdx.x;
  const int lane = tid & 63;
  const int w = tid >> 6;   // 0..7
  const int l = lane & 15;
  const int q = lane >> 4;
  const int mbase = blockIdx.x * MB;

  // ---- init LDS: zero [1] state buffers (h(-1)=0) + both XB buffers ----
  for (int idx = tid; idx < MB * 64; idx += 512) {
    int m = idx >> 6, k = idx & 63;
    H1[1][m * HSTR + k] = 0;
    H2[1][m * HSTR + k] = 0;
  }
  for (int idx = tid; idx < 2 * (MB * XSTR + XPAD); idx += 512) (&XB[0][0])[idx] = 0;
  if (tid < 256) {  // stage x(0)
    int m = tid >> 2, ii = tid & 3;
    XB[0][m * XSTR + ii] = f2h_(x[(mbase + m) * (T_ * I_) + ii]);
  }
  __syncthreads();

  if (w < 4) {
    // ==================== LAYER-1 WAVES (0..3) ====================
    const int j = w * 16 + l;  // hidden col owned (all 4 gates)
    half8 BX[4], WH[4][2];
    float bb0[4];
#pragma unroll
    for (int g = 0; g < 4; ++g) {
      BX[g] = wf[OFF_BX + g * 256 + w * 64 + lane];
#pragma unroll
      for (int hf = 0; hf < 2; ++hf)
        WH[g][hf] = wf[OFF_HH0 + (g * 2 + hf) * 256 + w * 64 + lane];
      bb0[g] = b0[g * 64 + j] * ((g == 2) ? SC_TANH : SC_SIG);
    }
    float c1[16];
#pragma unroll
    for (int k = 0; k < 16; ++k) c1[k] = 0.f;

#pragma unroll 1
    for (int tt = 0; tt < T_ + 1; ++tt) {
      if (tt < T_) {
        const int p = tt & 1;  // write h1(tt) -> H1[p]; read h1(tt-1) <- H1[p^1]
#pragma unroll
        for (int mt = 0; mt < 4; ++mt) {
          const int row = mt * 16 + l;
          half8 ah0 = *(const half8*)&H1[p ^ 1][row * HSTR + q * 8];
          half8 ah1 = *(const half8*)&H1[p ^ 1][row * HSTR + 32 + q * 8];
          half8 ax  = *(const half8*)&XB[p][row * XSTR + q * 8];
          floatx4 z0 = {bb0[0], bb0[0], bb0[0], bb0[0]};
          floatx4 z1 = {bb0[1], bb0[1], bb0[1], bb0[1]};
          floatx4 z2 = {bb0[2], bb0[2], bb0[2], bb0[2]};
          floatx4 z3 = {bb0[3], bb0[3], bb0[3], bb0[3]};
          R4X(z0, z1, z2, z3, ax,  BX[0],    BX[1],    BX[2],    BX[3])
          R4X(z0, z1, z2, z3, ah0, WH[0][0], WH[1][0], WH[2][0], WH[3][0])
          R4X(z0, z1, z2, z3, ah1, WH[0][1], WH[1][1], WH[2][1], WH[3][1])
#pragma unroll
          for (int r = 0; r < 4; ++r) {
            float si = sigm2_(z0[r]);
            float sf = sigm2_(z1[r]);
            float tg = tanhg_(z2[r]);
            float so = sigm2_(z3[r]);
            float cc = sf * c1[mt * 4 + r] + si * tg;
            c1[mt * 4 + r] = cc;
            float h = so * tanhc_(cc);
            const int m = mt * 16 + q * 4 + r;
            H1[p][m * HSTR + j] = f2h_(h);
          }
        }
        if (tt + 1 < T_) {  // stage x(tt+1) into the other XB buffer
          int m = (tid & 255) >> 2, ii = tid & 3;
          XB[(tt + 1) & 1][m * XSTR + ii] =
              f2h_(x[(mbase + m) * (T_ * I_) + (tt + 1) * I_ + ii]);
        }
      }
      __syncthreads();  // barrier 1-per-iter, matched with L2 branch
    }
  } else {
    // ==================== LAYER-2 WAVES (4..7) ====================
    const int w2 = w - 4;
    const int j = w2 * 16 + l;
    half8 IH[4][2], GH[4][2];  // Wih1, Whh1 frags
    float bb1[4];
#pragma unroll
    for (int g = 0; g < 4; ++g) {
#pragma unroll
      for (int hf = 0; hf < 2; ++hf) {
        IH[g][hf] = wf[OFF_IH1 + (g * 2 + hf) * 256 + w2 * 64 + lane];
        GH[g][hf] = wf[OFF_HH1 + (g * 2 + hf) * 256 + w2 * 64 + lane];
      }
      bb1[g] = b1[g * 64 + j] * ((g == 2) ? SC_TANH : SC_SIG);
    }
    float c2[16];
#pragma unroll
    for (int k = 0; k < 16; ++k) c2[k] = 0.f;

#pragma unroll 1
    for (int tt = 0; tt < T_ + 1; ++tt) {
      if (tt >= 1) {
        const int t2 = tt - 1;   // computing h2(t2)
        const int p2 = t2 & 1;   // read h1(t2) <- H1[p2], h2(t2-1) <- H2[p2^1]
        const bool do_out = (t2 % 5 == 4);
        const int kk = t2 / 5;
#pragma unroll
        for (int mt = 0; mt < 4; ++mt) {
          const int row = mt * 16 + l;
          half8 nh0 = *(const half8*)&H1[p2][row * HSTR + q * 8];
          half8 nh1 = *(const half8*)&H1[p2][row * HSTR + 32 + q * 8];
          half8 mh0 = *(const half8*)&H2[p2 ^ 1][row * HSTR + q * 8];
          half8 mh1 = *(const half8*)&H2[p2 ^ 1][row * HSTR + 32 + q * 8];
          floatx4 z0 = {bb1[0], bb1[0], bb1[0], bb1[0]};
          floatx4 z1 = {bb1[1], bb1[1], bb1[1], bb1[1]};
          floatx4 z2 = {bb1[2], bb1[2], bb1[2], bb1[2]};
          floatx4 z3 = {bb1[3], bb1[3], bb1[3], bb1[3]};
          R4X(z0, z1, z2, z3, nh0, IH[0][0], IH[1][0], IH[2][0], IH[3][0])
          R4X(z0, z1, z2, z3, nh1, IH[0][1], IH[1][1], IH[2][1], IH[3][1])
          R4X(z0, z1, z2, z3, mh0, GH[0][0], GH[1][0], GH[2][0], GH[3][0])
          R4X(z0, z1, z2, z3, mh1, GH[0][1], GH[1][1], GH[2][1], GH[3][1])
#pragma unroll
          for (int r = 0; r < 4; ++r) {
            float si = sigm2_(z0[r]);
            float sf = sigm2_(z1[r]);
            float tg = tanhg_(z2[r]);
            float so = sigm2_(z3[r]);
            float cc = sf * c2[mt * 4 + r] + si * tg;
            c2[mt * 4 + r] = cc;
            float h = so * tanhc_(cc);
            const int m = mt * 16 + q * 4 + r;
            H2[p2][m * HSTR + j] = f2h_(h);
            if (do_out) out[(size_t)(mbase + m) * 320 + (size_t)kk * 64 + j] = h;
          }
        }
      }
      __syncthreads();  // matched with L1 branch
    }
  }
}

#undef R4X

extern "C" void kernel_launch(void* const* d_in, const int* in_sizes, int n_in,
                              void* d_out, int out_size, void* d_ws, size_t ws_size,
                              hipStream_t stream) {
  const float* xp   = (const float*)d_in[0];
  const float* Wih0 = (const float*)d_in[1];
  const float* Whh0 = (const float*)d_in[2];
  const float* b0   = (const float*)d_in[3];
  const float* Wih1 = (const float*)d_in[4];
  const float* Whh1 = (const float*)d_in[5];
  const float* b1   = (const float*)d_in[6];
  float* outp = (float*)d_out;
  unsigned short* ws = (unsigned short*)d_ws;

  // Pre-scale + fp16-round weights into fragment-ordered arrays (114,688 B).
  hipLaunchKernelGGL(prep_weights, dim3(28), dim3(256), 0, stream,
                     Wih0, Whh0, Wih1, Whh1, ws);

  const int B = in_sizes[0] / (T_ * I_);  // 65536
  dim3 grid(B / MB), block(512);
  hipLaunchKernelGGL(lstm2_kernel, grid, block, 0, stream,
                     xp, b0, b1, (const half8*)ws, outp);
}